// Round 1
// baseline (62.412 us; speedup 1.0000x reference)
//
#include <hip/hip_runtime.h>
#include <math.h>

#define BATCH 4096
#define NX 256
#define NY 128

// ws layout (floats): WA[NX*NY] | WM[NX*NY] | WF[NX*NY] | G1[NY]
// WA[i*NY+j] = tanh(W_add[i,j])*sigmoid(M_add[i,j])
// WM[i*NY+j] = tanh(W_mul[i,j])*sigmoid(M_mul[i,j])
// WF[i*NY+j] = Wf[j,i] = |WM_mul_flat[j*NX+i]|  (reference's reshape(ny,nx))
// G1[j] = sigmoid(g[j])

__global__ void prep_kernel(const float* __restrict__ W_add,
                            const float* __restrict__ M_add,
                            const float* __restrict__ W_mul,
                            const float* __restrict__ M_mul,
                            const float* __restrict__ g,
                            float* __restrict__ ws) {
    int t = blockIdx.x * blockDim.x + threadIdx.x;
    float* WA = ws;
    float* WM = ws + NX * NY;
    float* WF = ws + 2 * NX * NY;
    float* G1 = ws + 3 * NX * NY;
    if (t < NX * NY) {
        float wa = tanhf(W_add[t]) * (1.f / (1.f + expf(-M_add[t])));
        float wm = tanhf(W_mul[t]) * (1.f / (1.f + expf(-M_mul[t])));
        WA[t] = wa;
        WM[t] = wm;
        // flat index t of WM_mul (row-major over (NX,NY)); goes to Wf[jf, if_]
        int jf  = t >> 8;        // t / NX  (NX=256)
        int if_ = t & (NX - 1);  // t % NX
        WF[if_ * NY + jf] = fabsf(wm);
    }
    if (t < NY) {
        G1[t] = 1.f / (1.f + expf(-g[t]));
    }
}

// 512 threads: j = tid & 127 (output col), q = tid >> 7 (row quad 0..3).
// Block handles 16 batch rows; each thread computes 4 rows x 1 col.
__global__ __launch_bounds__(512, 2)
void nalu_main(const float* __restrict__ x,
               const float* __restrict__ ws,
               float* __restrict__ out) {
    const float* __restrict__ WA = ws;
    const float* __restrict__ WM = ws + NX * NY;
    const float* __restrict__ WF = ws + 2 * NX * NY;
    const float* __restrict__ G1 = ws + 3 * NX * NY;

    __shared__ __align__(16) float xs[16][NX];  // x values
    __shared__ __align__(16) float ls[16][NX];  // log(max(|x|,1e-7))
    __shared__ __align__(16) float ss[16][NX];  // sign(x) in {-1,0,1}

    const int tid = threadIdx.x;
    const int j = tid & (NY - 1);
    const int q = tid >> 7;  // 0..3
    const int b0 = blockIdx.x * 16;

    // Stage 16 rows of x (+ derived log/sign) into LDS. Coalesced.
    for (int e = tid; e < 16 * NX; e += 512) {
        int r = e >> 8;        // e / NX
        int c = e & (NX - 1);  // e % NX
        float xv = x[(size_t)(b0 + r) * NX + c];
        xs[r][c] = xv;
        ls[r][c] = logf(fmaxf(fabsf(xv), 1e-7f));
        ss[r][c] = (xv > 0.f) ? 1.f : ((xv < 0.f) ? -1.f : 0.f);
    }
    __syncthreads();

    float acc_a[4] = {0.f, 0.f, 0.f, 0.f};
    float acc_l[4] = {0.f, 0.f, 0.f, 0.f};
    float acc_p[4] = {1.f, 1.f, 1.f, 1.f};
    const int r0 = q * 4;

    for (int i = 0; i < NX; i += 4) {
        float wa[4], wm[4], wf[4], omw[4];
#pragma unroll
        for (int u = 0; u < 4; ++u) {
            wa[u] = WA[(i + u) * NY + j];   // coalesced across lanes (j consecutive)
            wm[u] = WM[(i + u) * NY + j];
            wf[u] = WF[(i + u) * NY + j];
            omw[u] = 1.f - wf[u];
        }
#pragma unroll
        for (int r = 0; r < 4; ++r) {
            // wave-uniform addresses -> LDS broadcast, conflict-free
            const float4 xv = *reinterpret_cast<const float4*>(&xs[r0 + r][i]);
            const float4 lv = *reinterpret_cast<const float4*>(&ls[r0 + r][i]);
            const float4 sv = *reinterpret_cast<const float4*>(&ss[r0 + r][i]);
            const float* xp = &xv.x;
            const float* lp = &lv.x;
            const float* sp = &sv.x;
#pragma unroll
            for (int u = 0; u < 4; ++u) {
                acc_a[r] = fmaf(xp[u], wa[u], acc_a[r]);
                acc_l[r] = fmaf(lp[u], wm[u], acc_l[r]);
                acc_p[r] *= fmaf(sp[u], wf[u], omw[u]);  // sign*Wf + (1-Wf)
            }
        }
    }

    const float g1 = G1[j];
#pragma unroll
    for (int r = 0; r < 4; ++r) {
        float m1 = expf(fminf(acc_l[r], 20.f));
        float ms = fminf(fmaxf(acc_p[r], -1.f), 1.f);
        out[(size_t)(b0 + r0 + r) * NY + j] = g1 * acc_a[r] + (1.f - g1) * m1 * ms;
    }
}

extern "C" void kernel_launch(void* const* d_in, const int* in_sizes, int n_in,
                              void* d_out, int out_size, void* d_ws, size_t ws_size,
                              hipStream_t stream) {
    const float* x     = (const float*)d_in[0];
    const float* W_add = (const float*)d_in[1];
    const float* M_add = (const float*)d_in[2];
    const float* W_mul = (const float*)d_in[3];
    const float* M_mul = (const float*)d_in[4];
    const float* g     = (const float*)d_in[5];
    float* out = (float*)d_out;
    float* ws  = (float*)d_ws;  // needs 3*NX*NY + NY floats = ~384.5 KB

    prep_kernel<<<(NX * NY + 255) / 256, 256, 0, stream>>>(W_add, M_add, W_mul, M_mul, g, ws);
    nalu_main<<<BATCH / 16, 512, 0, stream>>>(x, ws, out);
}

// Round 2
// 18.230 us; speedup vs baseline: 3.4237x; 3.4237x over previous
//
#include <hip/hip_runtime.h>
#include <math.h>

#define BATCH 4096
#define NX 256   // K
#define NY 128   // N

typedef __attribute__((ext_vector_type(8))) short short8;
typedef __attribute__((ext_vector_type(4))) float f32x4;

// round-to-nearest-even float -> bf16 bits
static inline __device__ unsigned short f2bf(float f) {
    unsigned int u = __float_as_uint(f);
    u = (u + 0x7FFFu + ((u >> 16) & 1u)) >> 16;
    return (unsigned short)u;
}

static inline __device__ float sigmoidf_(float v) {
    return 1.f / (1.f + expf(-v));
}

// ws layout (ushort elems):
//   WAb [0, 32768)      : bf16 tanh(W_add)*sig(M_add), fragment-linear blobs
//   WMb [32768, 65536)  : bf16 tanh(W_mul)*sig(M_mul)
//   Lb  [65536, 98304)  : bf16 ln(max(|1-2*Wf|,1e-13))   (Wf = reference's reshuffled |WM_mul|)
//   NGb [98304, 131072) : bf16 indicator(1-2*Wf < 0)
// then at byte offset 262144: G1[128] f32 = sigmoid(g)
//
// Blob layout per matrix: blob (nt,kt) = (nt*8+kt), 64 lanes x 8 bf16 (16B/lane).
//   k = kt*32 + (lane>>4)*8 + e ; n = nt*16 + (lane&15)
__global__ void prep_kernel(const float* __restrict__ W_add,
                            const float* __restrict__ M_add,
                            const float* __restrict__ W_mul,
                            const float* __restrict__ M_mul,
                            const float* __restrict__ g,
                            unsigned short* __restrict__ wsb,
                            float* __restrict__ G1) {
    int p = blockIdx.x * 256 + threadIdx.x;   // 0..32767
    int nt   = p >> 12;
    int kt   = (p >> 9) & 7;
    int lane = (p >> 3) & 63;
    int e    = p & 7;
    int k = kt * 32 + (lane >> 4) * 8 + e;
    int n = nt * 16 + (lane & 15);
    int idx = k * NY + n;

    float wa = tanhf(W_add[idx]) * sigmoidf_(M_add[idx]);
    float wm = tanhf(W_mul[idx]) * sigmoidf_(M_mul[idx]);

    // Wf[j=n, i=k] = |WM_mul_flat[n*NX + k]| with flat row-major over (NX,NY)
    int f = n * NX + k;
    int idx2 = (f >> 7) * NY + (f & 127);
    float wmf = fabsf(tanhf(W_mul[idx2]) * sigmoidf_(M_mul[idx2]));
    float t2 = 1.f - 2.f * wmf;
    float L  = logf(fmaxf(fabsf(t2), 1e-13f));   // >= ~-29.9, avoids -inf
    float ng = (t2 < 0.f) ? 1.f : 0.f;

    wsb[p]          = f2bf(wa);
    wsb[32768 + p]  = f2bf(wm);
    wsb[65536 + p]  = f2bf(L);
    wsb[98304 + p]  = f2bf(ng);

    if (p < NY) G1[p] = sigmoidf_(g[p]);
}

// 512 blocks x 256 threads. Block: 16 batch rows x 64 cols. Wave: 16x16 tile.
// 4 fused GEMM paths per tile via mfma_f32_16x16x32_bf16, K=256 in 8 steps.
__global__ __launch_bounds__(256, 2)
void nalu_mfma(const float* __restrict__ x,
               const unsigned short* __restrict__ wsb,
               const float* __restrict__ G1,
               float* __restrict__ out) {
    const int tid  = threadIdx.x;
    const int wave = tid >> 6;
    const int lane = tid & 63;
    const int mt = blockIdx.x >> 1;   // 0..255
    const int nb = blockIdx.x & 1;    // 0..1
    const int b0 = mt * 16;
    const int ntg = nb * 4 + wave;    // global 16-col tile 0..7
    const int arow = lane & 15;       // A-fragment row
    const int kg   = lane >> 4;       // k-group 0..3

    const short8* __restrict__ WA = (const short8*)wsb;
    const short8* __restrict__ WM = WA + 4096;
    const short8* __restrict__ LB = WA + 8192;
    const short8* __restrict__ NG = WA + 12288;

    f32x4 accA = {0.f, 0.f, 0.f, 0.f};
    f32x4 accL = {0.f, 0.f, 0.f, 0.f};
    f32x4 accC = {0.f, 0.f, 0.f, 0.f};
    f32x4 accP = {0.f, 0.f, 0.f, 0.f};

    const float* __restrict__ xrow = x + (size_t)(b0 + arow) * NX + kg * 8;

#pragma unroll
    for (int kt = 0; kt < 8; ++kt) {
        // ---- A fragments: read 8 consecutive f32 of x, derive 3 operands ----
        f32x4 xv0 = *(const f32x4*)(xrow + kt * 32);
        f32x4 xv1 = *(const f32x4*)(xrow + kt * 32 + 4);
        short8 xs8, ls8, ns8;
#pragma unroll
        for (int e = 0; e < 8; ++e) {
            float v = (e < 4) ? xv0[e] : xv1[e - 4];
            xs8[e] = (short)f2bf(v);
            ls8[e] = (short)f2bf(logf(fmaxf(fabsf(v), 1e-7f)));
            ns8[e] = (v < 0.f) ? (short)0x3F80 : (short)0;   // bf16 1.0 / 0.0
        }
        // ---- B fragments: fragment-linear blobs, 16B/lane fully coalesced ----
        const int bi = (ntg * 8 + kt) * 64 + lane;
        short8 wa = WA[bi];
        short8 wm = WM[bi];
        short8 lb = LB[bi];
        short8 ng = NG[bi];

        accA = __builtin_amdgcn_mfma_f32_16x16x32_bf16(xs8, wa, accA, 0, 0, 0);
        accL = __builtin_amdgcn_mfma_f32_16x16x32_bf16(ls8, wm, accL, 0, 0, 0);
        accC = __builtin_amdgcn_mfma_f32_16x16x32_bf16(ns8, lb, accC, 0, 0, 0);
        accP = __builtin_amdgcn_mfma_f32_16x16x32_bf16(ns8, ng, accP, 0, 0, 0);
    }

    // ---- epilogue: D layout col=lane&15, row=(lane>>4)*4+v ----
    const int col = ntg * 16 + (lane & 15);
    const float g1 = G1[col];
#pragma unroll
    for (int v = 0; v < 4; ++v) {
        float a1  = accA[v];
        float m1  = expf(fminf(accL[v], 20.f));
        float msa = expf(accC[v]);              // <= 1 by construction
        int   par = __float2int_rn(accP[v]);
        float ms1 = (par & 1) ? -msa : msa;
        ms1 = fminf(fmaxf(ms1, -1.f), 1.f);
        out[(size_t)(b0 + kg * 4 + v) * NY + col] = g1 * a1 + (1.f - g1) * m1 * ms1;
    }
}

extern "C" void kernel_launch(void* const* d_in, const int* in_sizes, int n_in,
                              void* d_out, int out_size, void* d_ws, size_t ws_size,
                              hipStream_t stream) {
    const float* x     = (const float*)d_in[0];
    const float* W_add = (const float*)d_in[1];
    const float* M_add = (const float*)d_in[2];
    const float* W_mul = (const float*)d_in[3];
    const float* M_mul = (const float*)d_in[4];
    const float* g     = (const float*)d_in[5];
    float* out = (float*)d_out;

    unsigned short* wsb = (unsigned short*)d_ws;
    float* G1 = (float*)((char*)d_ws + 262144);

    prep_kernel<<<128, 256, 0, stream>>>(W_add, M_add, W_mul, M_mul, g, wsb, G1);
    nalu_mfma<<<512, 256, 0, stream>>>(x, wsb, G1, out);
}

// Round 3
// 15.884 us; speedup vs baseline: 3.9293x; 1.1477x over previous
//
#include <hip/hip_runtime.h>
#include <math.h>

#define BATCH 4096
#define NX 256   // K
#define NY 128   // N

typedef __attribute__((ext_vector_type(8))) short short8;
typedef __attribute__((ext_vector_type(4))) float f32x4;

// round-to-nearest-even float -> bf16 bits
static inline __device__ unsigned short f2bf(float f) {
    unsigned int u = __float_as_uint(f);
    u = (u + 0x7FFFu + ((u >> 16) & 1u)) >> 16;
    return (unsigned short)u;
}
static inline __device__ float fsig(float v) {
    return __fdividef(1.f, 1.f + __expf(-v));
}
static inline __device__ float ftanh(float v) {
    float e = __expf(2.f * v);
    return __fdividef(e - 1.f, e + 1.f);
}

// ws layout (ushort elems):
//   WAb [0, 32768)      : bf16 tanh(W_add)*sig(M_add), fragment-linear blobs
//   WMb [32768, 65536)  : bf16 tanh(W_mul)*sig(M_mul)
//   Lb  [65536, 98304)  : bf16 ln(max(|1-2*Wf|,1e-13))
//   NGb [98304, 131072) : bf16 indicator(1-2*Wf < 0)
// byte 262144: G1[128] f32 = sigmoid(g)
// Blob layout: blob (nt,kt) = nt*8+kt, 64 lanes x 8 bf16.
//   k = kt*32 + (lane>>4)*8 + e ; n = nt*16 + (lane&15)   [validated R2]
__global__ void prep_kernel(const float* __restrict__ W_add,
                            const float* __restrict__ M_add,
                            const float* __restrict__ W_mul,
                            const float* __restrict__ M_mul,
                            const float* __restrict__ g,
                            unsigned short* __restrict__ wsb,
                            float* __restrict__ G1) {
    int p = blockIdx.x * 256 + threadIdx.x;   // 0..32767
    int nt   = p >> 12;
    int kt   = (p >> 9) & 7;
    int lane = (p >> 3) & 63;
    int e    = p & 7;
    int k = kt * 32 + (lane >> 4) * 8 + e;
    int n = nt * 16 + (lane & 15);
    int idx = k * NY + n;

    float wa = ftanh(W_add[idx]) * fsig(M_add[idx]);
    float wm = ftanh(W_mul[idx]) * fsig(M_mul[idx]);

    // Wf[j=n, i=k] = |WM_mul_flat[n*NX + k]|, flat row-major over (NX,NY)
    int f = n * NX + k;
    int idx2 = (f >> 7) * NY + (f & 127);
    float wmf = fabsf(ftanh(W_mul[idx2]) * fsig(M_mul[idx2]));
    float t2 = 1.f - 2.f * wmf;
    float L  = __logf(fmaxf(fabsf(t2), 1e-13f));
    float ng = (t2 < 0.f) ? 1.f : 0.f;

    wsb[p]          = f2bf(wa);
    wsb[32768 + p]  = f2bf(wm);
    wsb[65536 + p]  = f2bf(L);
    wsb[98304 + p]  = f2bf(ng);

    if (p < NY) G1[p] = fsig(g[p]);
}

// 256 blocks x 512 threads (8 waves). Block: 16 batch rows x all 128 cols.
// Wave w computes col-tile w. Conversion phase: thread tid converts the
// exact A-fragment that lane tid&63 reads at kt=tid>>6 -> LDS chunk = tid.
// Linear 16B/lane LDS chunks: conflict-free writes and reads.
__global__ __launch_bounds__(512, 2)
void nalu_mfma(const float* __restrict__ x,
               const unsigned short* __restrict__ wsb,
               const float* __restrict__ G1,
               float* __restrict__ out) {
    __shared__ short8 XB[512];
    __shared__ short8 LBs[512];
    __shared__ short8 NBs[512];

    const int tid  = threadIdx.x;
    const int wave = tid >> 6;     // conversion: kt ; compute: ntg
    const int lane = tid & 63;
    const int kg   = lane >> 4;    // 0..3
    const int row  = lane & 15;    // 0..15
    const int b0   = blockIdx.x * 16;

    // ---- conversion phase: 8 elems/thread, once per element globally ----
    {
        const float* xp = x + (size_t)(b0 + row) * NX + wave * 32 + kg * 8;
        f32x4 v0 = *(const f32x4*)xp;
        f32x4 v1 = *(const f32x4*)(xp + 4);
        short8 xb, lb, nb;
#pragma unroll
        for (int e = 0; e < 8; ++e) {
            float v = (e < 4) ? v0[e] : v1[e - 4];
            xb[e] = (short)f2bf(v);
            lb[e] = (short)f2bf(__logf(fmaxf(fabsf(v), 1e-7f)));
            nb[e] = (v < 0.f) ? (short)0x3F80 : (short)0;   // bf16 1.0/0.0
        }
        XB[tid] = xb; LBs[tid] = lb; NBs[tid] = nb;
    }
    __syncthreads();

    const short8* __restrict__ WA = (const short8*)wsb;
    const short8* __restrict__ WM = WA + 4096;
    const short8* __restrict__ LW = WA + 8192;
    const short8* __restrict__ NG = WA + 12288;

    f32x4 accA = {0.f, 0.f, 0.f, 0.f};
    f32x4 accL = {0.f, 0.f, 0.f, 0.f};
    f32x4 accC = {0.f, 0.f, 0.f, 0.f};
    f32x4 accP = {0.f, 0.f, 0.f, 0.f};

#pragma unroll
    for (int kt = 0; kt < 8; ++kt) {
        short8 xa = XB[kt * 64 + lane];
        short8 la = LBs[kt * 64 + lane];
        short8 na = NBs[kt * 64 + lane];
        const int bi = (wave * 8 + kt) * 64 + lane;
        accA = __builtin_amdgcn_mfma_f32_16x16x32_bf16(xa, WA[bi], accA, 0, 0, 0);
        accL = __builtin_amdgcn_mfma_f32_16x16x32_bf16(la, WM[bi], accL, 0, 0, 0);
        accC = __builtin_amdgcn_mfma_f32_16x16x32_bf16(na, LW[bi], accC, 0, 0, 0);
        accP = __builtin_amdgcn_mfma_f32_16x16x32_bf16(na, NG[bi], accP, 0, 0, 0);
    }

    // ---- epilogue: D layout col=lane&15, row=(lane>>4)*4+v  [validated R2] ----
    const int col = wave * 16 + row;
    const float g1 = G1[col];
#pragma unroll
    for (int v = 0; v < 4; ++v) {
        float a1  = accA[v];
        float m1  = __expf(fminf(accL[v], 20.f));
        float msa = __expf(accC[v]);           // <= 1 by construction
        int   par = __float2int_rn(accP[v]);
        float ms1 = (par & 1) ? -msa : msa;
        ms1 = fminf(fmaxf(ms1, -1.f), 1.f);
        out[(size_t)(b0 + kg * 4 + v) * NY + col] = g1 * a1 + (1.f - g1) * m1 * ms1;
    }
}

extern "C" void kernel_launch(void* const* d_in, const int* in_sizes, int n_in,
                              void* d_out, int out_size, void* d_ws, size_t ws_size,
                              hipStream_t stream) {
    const float* x     = (const float*)d_in[0];
    const float* W_add = (const float*)d_in[1];
    const float* M_add = (const float*)d_in[2];
    const float* W_mul = (const float*)d_in[3];
    const float* M_mul = (const float*)d_in[4];
    const float* g     = (const float*)d_in[5];
    float* out = (float*)d_out;

    unsigned short* wsb = (unsigned short*)d_ws;
    float* G1 = (float*)((char*)d_ws + 262144);

    prep_kernel<<<128, 256, 0, stream>>>(W_add, M_add, W_mul, M_mul, g, wsb, G1);
    nalu_mfma<<<BATCH / 16, 512, 0, stream>>>(x, wsb, G1, out);
}

// Round 4
// 15.199 us; speedup vs baseline: 4.1062x; 1.0450x over previous
//
#include <hip/hip_runtime.h>
#include <math.h>

#define BATCH 4096
#define NX 256   // K
#define NY 128   // N

typedef __attribute__((ext_vector_type(8))) short short8;
typedef __attribute__((ext_vector_type(4))) float f32x4;

// round-to-nearest-even float -> bf16 bits
static inline __device__ unsigned short f2bf(float f) {
    unsigned int u = __float_as_uint(f);
    u = (u + 0x7FFFu + ((u >> 16) & 1u)) >> 16;
    return (unsigned short)u;
}
static inline __device__ float fsig(float v) {
    return __fdividef(1.f, 1.f + __expf(-v));
}
static inline __device__ float ftanh(float v) {
    float e = __expf(2.f * v);
    return __fdividef(e - 1.f, e + 1.f);
}

// Blob layout per matrix [validated R2/R3]: element for (k, n) lives at
//   p = (nt<<12) | (kt<<9) | (lane<<3) | e
//   with kt=k>>5, kg=(k>>3)&3, e=k&7, nt=n>>4, lane=(kg<<4)|(n&15)
static inline __device__ int bpos(int k, int n) {
    int kt = k >> 5, kg = (k >> 3) & 3, e = k & 7;
    int nt = n >> 4, lane = (kg << 4) | (n & 15);
    return (nt << 12) | (kt << 9) | (lane << 3) | e;
}

// ws (ushort): WAb[0,32K) | WMb[32K,64K) | Lb[64K,96K) | NGb[96K,128K)
// byte 262144: G1[128] f32.
// Scatter form: thread owns flat p0 = i*NY+j; computes each tanh/sig ONCE.
// Its wm value is Wf[jf, if] with jf = p0>>8, if = p0&255 (flat = jf*NX+if),
// so L/NG derived from wm go to blob slot (k=if, n=jf).
__global__ void prep_kernel(const float* __restrict__ W_add,
                            const float* __restrict__ M_add,
                            const float* __restrict__ W_mul,
                            const float* __restrict__ M_mul,
                            const float* __restrict__ g,
                            unsigned short* __restrict__ wsb,
                            float* __restrict__ G1) {
    int p0 = blockIdx.x * 128 + threadIdx.x;   // 0..32767 = i*NY+j
    int i = p0 >> 7;      // k
    int j = p0 & 127;     // n

    float wa = ftanh(W_add[p0]) * fsig(M_add[p0]);
    float wm = ftanh(W_mul[p0]) * fsig(M_mul[p0]);

    int pa = bpos(i, j);
    wsb[pa]         = f2bf(wa);
    wsb[32768 + pa] = f2bf(wm);

    int jf  = p0 >> 8;    // n index for L/NG
    int if_ = p0 & 255;   // k index
    float t2 = 1.f - 2.f * fabsf(wm);
    float L  = __logf(fmaxf(fabsf(t2), 1e-13f));
    int pl = bpos(if_, jf);
    wsb[65536 + pl] = f2bf(L);
    wsb[98304 + pl] = (t2 < 0.f) ? (unsigned short)0x3F80 : (unsigned short)0;

    if (p0 < NY) G1[p0] = fsig(g[p0]);
}

// 512 blocks x 256 threads (4 waves). Block: 16 rows x 64 cols (nb = col half).
// 2 blocks/CU. Conversion: chunk c -> kt=c>>6, lane'=c&63; perfect LDS + 128B
// global segments [validated R3]. B loads pre-issued before the barrier,
// rolling 2-deep prefetch in the kt loop (kt&1 is compile-time under unroll).
__global__ __launch_bounds__(256, 2)
void nalu_mfma(const float* __restrict__ x,
               const unsigned short* __restrict__ wsb,
               const float* __restrict__ G1,
               float* __restrict__ out) {
    __shared__ short8 XB[512];
    __shared__ short8 LBs[512];
    __shared__ short8 NBs[512];

    const int tid  = threadIdx.x;
    const int wave = tid >> 6;
    const int lane = tid & 63;
    const int kg   = lane >> 4;
    const int row  = lane & 15;
    const int mt   = blockIdx.x >> 1;
    const int nb   = blockIdx.x & 1;
    const int b0   = mt * 16;
    const int ntg  = nb * 4 + wave;    // global 16-col tile

    const short8* __restrict__ WA = (const short8*)wsb;
    const short8* __restrict__ WM = WA + 4096;
    const short8* __restrict__ LW = WA + 8192;
    const short8* __restrict__ NG = WA + 12288;

    // ---- pre-issue B loads for kt = 0,1 (latency hides under conversion) ----
    short8 bwa[2], bwm[2], blw[2], bng[2];
    {
        const int bi0 = (ntg * 8 + 0) * 64 + lane;
        const int bi1 = (ntg * 8 + 1) * 64 + lane;
        bwa[0] = WA[bi0]; bwm[0] = WM[bi0]; blw[0] = LW[bi0]; bng[0] = NG[bi0];
        bwa[1] = WA[bi1]; bwm[1] = WM[bi1]; blw[1] = LW[bi1]; bng[1] = NG[bi1];
    }
    const float g1 = G1[ntg * 16 + row];

    // ---- conversion: 2 chunks/thread, once per element in block ----
#pragma unroll
    for (int it = 0; it < 2; ++it) {
        const int c    = tid + it * 256;
        const int ckt  = c >> 6;
        const int cl   = c & 63;
        const int crow = cl & 15;
        const int ckg  = cl >> 4;
        const float* xp = x + (size_t)(b0 + crow) * NX + ckt * 32 + ckg * 8;
        f32x4 v0 = *(const f32x4*)xp;
        f32x4 v1 = *(const f32x4*)(xp + 4);
        short8 xb, lb, nb8;
#pragma unroll
        for (int e = 0; e < 8; ++e) {
            float v = (e < 4) ? v0[e] : v1[e - 4];
            xb[e] = (short)f2bf(v);
            lb[e] = (short)f2bf(__logf(fmaxf(fabsf(v), 1e-7f)));
            nb8[e] = (v < 0.f) ? (short)0x3F80 : (short)0;
        }
        XB[c] = xb; LBs[c] = lb; NBs[c] = nb8;
    }
    __syncthreads();

    f32x4 accA = {0.f, 0.f, 0.f, 0.f};
    f32x4 accL = {0.f, 0.f, 0.f, 0.f};
    f32x4 accC = {0.f, 0.f, 0.f, 0.f};
    f32x4 accP = {0.f, 0.f, 0.f, 0.f};

#pragma unroll
    for (int kt = 0; kt < 8; ++kt) {
        short8 xa = XB[kt * 64 + lane];
        short8 la = LBs[kt * 64 + lane];
        short8 na = NBs[kt * 64 + lane];
        const int s = kt & 1;
        short8 wa = bwa[s], wm = bwm[s], lw = blw[s], ng = bng[s];
        if (kt + 2 < 8) {   // rolling prefetch into the slot just consumed
            const int bi = (ntg * 8 + kt + 2) * 64 + lane;
            bwa[s] = WA[bi]; bwm[s] = WM[bi]; blw[s] = LW[bi]; bng[s] = NG[bi];
        }
        accA = __builtin_amdgcn_mfma_f32_16x16x32_bf16(xa, wa, accA, 0, 0, 0);
        accL = __builtin_amdgcn_mfma_f32_16x16x32_bf16(la, wm, accL, 0, 0, 0);
        accC = __builtin_amdgcn_mfma_f32_16x16x32_bf16(na, lw, accC, 0, 0, 0);
        accP = __builtin_amdgcn_mfma_f32_16x16x32_bf16(na, ng, accP, 0, 0, 0);
    }

    // ---- epilogue: D layout col=lane&15, row=(lane>>4)*4+v [validated R2] ----
    const int col = ntg * 16 + row;
#pragma unroll
    for (int v = 0; v < 4; ++v) {
        float a1  = accA[v];
        float m1  = __expf(fminf(accL[v], 20.f));
        float msa = __expf(accC[v]);
        int   par = __float2int_rn(accP[v]);
        float ms1 = (par & 1) ? -msa : msa;
        ms1 = fminf(fmaxf(ms1, -1.f), 1.f);
        out[(size_t)(b0 + kg * 4 + v) * NY + col] = g1 * a1 + (1.f - g1) * m1 * ms1;
    }
}

extern "C" void kernel_launch(void* const* d_in, const int* in_sizes, int n_in,
                              void* d_out, int out_size, void* d_ws, size_t ws_size,
                              hipStream_t stream) {
    const float* x     = (const float*)d_in[0];
    const float* W_add = (const float*)d_in[1];
    const float* M_add = (const float*)d_in[2];
    const float* W_mul = (const float*)d_in[3];
    const float* M_mul = (const float*)d_in[4];
    const float* g     = (const float*)d_in[5];
    float* out = (float*)d_out;

    unsigned short* wsb = (unsigned short*)d_ws;
    float* G1 = (float*)((char*)d_ws + 262144);

    prep_kernel<<<256, 128, 0, stream>>>(W_add, M_add, W_mul, M_mul, g, wsb, G1);
    nalu_mfma<<<512, 256, 0, stream>>>(x, wsb, G1, out);
}